// Round 3
// baseline (891.507 us; speedup 1.0000x reference)
//
#include <hip/hip_runtime.h>

#define NN 5000
#define NE 50000
#define LL 9
#define CC 128
#define NH 8
#define VCD 16
#define DR 128
#define AE 64
#define MZ 100

#define AP 129   // f32 A-tile row stride (words): bank-conflict-free
#define BP 66    // u32 B-tile row stride

typedef unsigned int u32;
typedef unsigned short u16;

// ---------- bf16 helpers ----------
__device__ __forceinline__ float bf_lo(u32 u){ return __uint_as_float(u << 16); }
__device__ __forceinline__ float bf_hi(u32 u){ return __uint_as_float(u & 0xffff0000u); }
__device__ __forceinline__ u16 f2bf(float f){
  u32 u = __float_as_uint(f);
  u32 r = (u + 0x7fffu + ((u >> 16) & 1u)) >> 16;  // RNE
  return (u16)r;
}
__device__ __forceinline__ u32 pack2(float a, float b){
  return (u32)f2bf(a) | ((u32)f2bf(b) << 16);
}
// ordered-float <-> uint monotone map for atomicMax on f32
__device__ __forceinline__ u32 encf(float f){
  u32 u = __float_as_uint(f);
  return (u & 0x80000000u) ? ~u : (u | 0x80000000u);
}
__device__ __forceinline__ float decf(u32 k){
  u32 u = (k & 0x80000000u) ? (k & 0x7fffffffu) : ~k;
  return __uint_as_float(u);
}
__device__ __forceinline__ float sigmoidf_(float x){ return 1.f / (1.f + __expf(-x)); }

// ---------- GEMM tile: 32 rows x 128 cols, K=128; A f32 in LDS, B bf16-packed ----------
__device__ __forceinline__ void gemm_32x128(const float* Asf, const u32* Bs,
                                            int r0, int cq, float* acc)
{
  #pragma unroll 2
  for (int kp = 0; kp < 64; ++kp) {
    float al[4], ah[4];
    #pragma unroll
    for (int i = 0; i < 4; ++i) {
      al[i] = Asf[(r0 + i) * AP + 2 * kp];
      ah[i] = Asf[(r0 + i) * AP + 2 * kp + 1];
    }
    u32 b0 = Bs[(2 * kp) * BP + 2 * cq];
    u32 b1 = Bs[(2 * kp) * BP + 2 * cq + 1];
    u32 b2 = Bs[(2 * kp + 1) * BP + 2 * cq];
    u32 b3 = Bs[(2 * kp + 1) * BP + 2 * cq + 1];
    float bl[4] = { bf_lo(b0), bf_hi(b0), bf_lo(b1), bf_hi(b1) };
    float bh[4] = { bf_lo(b2), bf_hi(b2), bf_lo(b3), bf_hi(b3) };
    #pragma unroll
    for (int i = 0; i < 4; ++i)
      #pragma unroll
      for (int j = 0; j < 4; ++j)
        acc[i * 4 + j] += al[i] * bl[j] + ah[i] * bh[j];
  }
}

// ---------- K0: tables + zero-init ----------
__global__ void k0_tables(const float* __restrict__ ae_v, const float* __restrict__ wr1_v,
                          const float* __restrict__ ae_d, const float* __restrict__ wr1_d,
                          const float* __restrict__ wval_v, const float* __restrict__ wproj_v,
                          const float* __restrict__ wval_d, const float* __restrict__ wproj_d,
                          float* __restrict__ radz, float* __restrict__ wpv,
                          u32* __restrict__ mkey, float* __restrict__ den, float* __restrict__ acc)
{
  int idx = blockIdx.x * 256 + threadIdx.x;
  if (idx < 2 * 2 * MZ * CC) {   // radz[tag][sd][z][c]
    int c = idx & 127;
    int z = (idx >> 7) % MZ;
    int sd = (idx / (128 * MZ)) & 1;
    int tag = idx / (128 * MZ * 2);
    const float* ae = tag ? ae_d : ae_v;
    const float* w  = tag ? wr1_d : wr1_v;
    float s = 0.f;
    for (int a = 0; a < AE; ++a)
      s += ae[z * AE + a] * w[(DR + sd * AE + a) * CC + c];
    radz[idx] = s;
  }
  int i2 = idx - 2 * 2 * MZ * CC;
  if (i2 >= 0 && i2 < 2 * CC * NH) {   // wpv[tag][c][h]
    int h = i2 & 7;
    int c = (i2 >> 3) & 127;
    int tag = i2 >> 10;
    const float* wv = tag ? wval_d : wval_v;
    const float* wp = tag ? wproj_d : wproj_v;
    float s = 0.f;
    for (int q = 0; q < VCD; ++q) s += wv[c * (NH * VCD) + h * VCD + q] * wp[h * VCD + q];
    wpv[i2] = s;
  }
  int i3 = i2 - 2 * CC * NH;
  if (i3 >= 0 && i3 < 2 * NN * NH) mkey[i3] = 0u;
  int i4 = i3 - 2 * NN * NH;
  if (i4 >= 0 && i4 < 2 * NN * NH) den[i4] = 0.f;
  int i5 = i4 - 2 * NN * NH;
  if (i5 >= 0 && i5 < 2 * NN * 3) acc[i5] = 0.f;
}

// ---------- K0b: detect mask storage format ----------
__global__ void k0_flag(const u32* __restrict__ mw, int* __restrict__ flag)
{
  __shared__ int bad;
  if (threadIdx.x == 0) bad = 0;
  __syncthreads();
  int lbad = 0;
  for (int i = threadIdx.x; i < 1248; i += 256)
    if (mw[i] > 1u) lbad = 1;
  if (lbad) bad = 1;
  __syncthreads();
  if (threadIdx.x == 0) *flag = bad;   // 1 => bytes, 0 => int32
}

// ---------- K1: P[n*9+j][chunk*128+c] = x-row @ W_msg-half (bf16 out) ----------
__global__ __launch_bounds__(256) void k1_nodepre(const float* __restrict__ x,
                                                  const float* __restrict__ wmsg_v,
                                                  const float* __restrict__ wmsg_d,
                                                  u16* __restrict__ Pall)
{
  __shared__ float Asf[32 * AP];
  __shared__ u32 Bs[128 * BP];
  int t = threadIdx.x;
  int chunk = blockIdx.y;                               // 0..3
  const float* B = (chunk >= 2 ? wmsg_d : wmsg_v) + (chunk & 1) * 128 * CC;
  int row0 = blockIdx.x * 32;
  for (int i = t; i < 128 * 64; i += 256) {
    int k = i >> 6, cp = i & 63;
    Bs[k * BP + cp] = pack2(B[k * CC + 2 * cp], B[k * CC + 2 * cp + 1]);
  }
  for (int i = t; i < 32 * 128; i += 256) {
    int r = i >> 7, c = i & 127;
    int row = row0 + r;
    Asf[r * AP + c] = (row < NN * LL) ? x[(size_t)row * CC + c] : 0.f;
  }
  __syncthreads();
  int rq = t & 7, cq = t >> 3;
  int r0 = rq * 4, c0 = cq * 4;
  float acc[16] = {};
  gemm_32x128(Asf, Bs, r0, cq, acc);
  int colbase = chunk * 128;
  u32* P32 = (u32*)Pall;
  #pragma unroll
  for (int i = 0; i < 4; ++i) {
    int row = row0 + r0 + i;
    if (row < NN * LL) {
      size_t base = ((size_t)row * 512 + colbase + c0) >> 1;
      P32[base]     = pack2(acc[i * 4 + 0], acc[i * 4 + 1]);
      P32[base + 1] = pack2(acc[i * 4 + 2], acc[i * 4 + 3]);
    }
  }
}

// ---------- K2: h1 = silu(edist @ W_rad1[0:128] + radz_s + radz_d)  (bf16-packed out) ----------
__global__ __launch_bounds__(256) void k2_rad1(const float* __restrict__ edist,
                                               const float* __restrict__ wr1_v,
                                               const float* __restrict__ wr1_d,
                                               const int* __restrict__ eidx,
                                               const int* __restrict__ zn,
                                               const float* __restrict__ radz,
                                               u32* __restrict__ h1rad)
{
  __shared__ float Asf[32 * AP];
  __shared__ u32 Bs[128 * BP];
  __shared__ int zsrc[32], zdst[32];
  int t = threadIdx.x;
  int tag = blockIdx.y;
  const float* B = tag ? wr1_d : wr1_v;
  int e0 = blockIdx.x * 32;
  for (int i = t; i < 128 * 64; i += 256) {
    int k = i >> 6, cp = i & 63;
    Bs[k * BP + cp] = pack2(B[k * CC + 2 * cp], B[k * CC + 2 * cp + 1]);
  }
  for (int i = t; i < 32 * 128; i += 256) {
    int r = i >> 7, c = i & 127;
    int e = e0 + r;
    Asf[r * AP + c] = (e < NE) ? edist[(size_t)e * DR + c] : 0.f;
  }
  if (t < 32) {
    int e = e0 + t;
    int s = 0, d = 0;
    if (e < NE) { s = eidx[e]; d = eidx[NE + e]; }
    zsrc[t] = zn[s];
    zdst[t] = zn[d];
  }
  __syncthreads();
  int rq = t & 7, cq = t >> 3;
  int r0 = rq * 4, c0 = cq * 4;
  float acc[16] = {};
  gemm_32x128(Asf, Bs, r0, cq, acc);
  const float* rz_s = radz + tag * 2 * MZ * CC;
  const float* rz_d = rz_s + MZ * CC;
  #pragma unroll
  for (int i = 0; i < 4; ++i) {
    int e = e0 + r0 + i;
    if (e < NE) {
      int zs = zsrc[r0 + i], zd = zdst[r0 + i];
      float o[4];
      #pragma unroll
      for (int j = 0; j < 4; ++j) {
        float v = acc[i * 4 + j] + rz_s[zs * CC + c0 + j] + rz_d[zd * CC + c0 + j];
        o[j] = v * sigmoidf_(v);
      }
      size_t base = ((size_t)tag * NE * CC + (size_t)e * CC + c0) >> 1;
      h1rad[base]     = pack2(o[0], o[1]);
      h1rad[base + 1] = pack2(o[2], o[3]);
    }
  }
}

// ---------- K3: rad = h1 @ W_rad2, written IN PLACE over h1 (bf16-packed) ----------
__global__ __launch_bounds__(256) void k3_rad2(u32* h1rad,
                                               const float* __restrict__ wr2_v,
                                               const float* __restrict__ wr2_d)
{
  __shared__ float Asf[32 * AP];
  __shared__ u32 Bs[128 * BP];
  int t = threadIdx.x;
  int tag = blockIdx.y;
  const float* B = tag ? wr2_d : wr2_v;
  int e0 = blockIdx.x * 32;
  for (int i = t; i < 128 * 64; i += 256) {
    int k = i >> 6, cp = i & 63;
    Bs[k * BP + cp] = pack2(B[k * CC + 2 * cp], B[k * CC + 2 * cp + 1]);
  }
  for (int i = t; i < 32 * 64; i += 256) {
    int r = i >> 6, kp = i & 63;
    int e = e0 + r;
    u32 v = (e < NE) ? h1rad[((size_t)tag * NE * CC) / 2 + (size_t)e * 64 + kp] : 0u;
    Asf[r * AP + 2 * kp]     = bf_lo(v);
    Asf[r * AP + 2 * kp + 1] = bf_hi(v);
  }
  __syncthreads();    // all reads of this block's rows complete before any write below
  int rq = t & 7, cq = t >> 3;
  int r0 = rq * 4, c0 = cq * 4;
  float acc[16] = {};
  gemm_32x128(Asf, Bs, r0, cq, acc);
  #pragma unroll
  for (int i = 0; i < 4; ++i) {
    int e = e0 + r0 + i;
    if (e < NE) {
      size_t base = ((size_t)tag * NE * CC + (size_t)e * CC + c0) >> 1;
      h1rad[base]     = pack2(acc[i * 4 + 0], acc[i * 4 + 1]);
      h1rad[base + 1] = pack2(acc[i * 4 + 2], acc[i * 4 + 3]);
    }
  }
}

// ---------- K4: logits + segment max ----------
__global__ __launch_bounds__(256) void k4_logits(const u16* __restrict__ Pall,
                                                 const float* __restrict__ wig,
                                                 const u32* __restrict__ radP,
                                                 const float* __restrict__ wal_v,
                                                 const float* __restrict__ wal_d,
                                                 const float* __restrict__ av_v,
                                                 const float* __restrict__ av_d,
                                                 const int* __restrict__ eidx,
                                                 float* __restrict__ logits,
                                                 u32* __restrict__ mkey)
{
  __shared__ float Asf[32 * AP];
  __shared__ u32 Bs[128 * BP];
  __shared__ float wig0s[32][9];
  __shared__ int esrc[32], edst[32];
  __shared__ float ltile[32][8];
  int t = threadIdx.x;
  int tag = blockIdx.y;
  const float* B  = tag ? wal_d : wal_v;    // (128,256)
  const float* av = tag ? av_d : av_v;      // (8,32)
  int e0 = blockIdx.x * 32;
  if (t < 32) {
    int e = e0 + t;
    int s = 0, d = 0;
    if (e < NE) { s = eidx[e]; d = eidx[NE + e]; }
    esrc[t] = s; edst[t] = d;
  }
  ltile[t >> 3][t & 7] = 0.f;
  for (int i = t; i < 32 * 9; i += 256) {
    int el = i / 9, j = i % 9;
    int e = e0 + el;
    wig0s[el][j] = (e < NE) ? wig[(size_t)e * 81 + j] : 0.f;
  }
  __syncthreads();
  {  // A = m0r = (row-0 wigner combine of P_src+P_dst) * rad
    int el = t >> 3, pp = t & 7;
    int e = e0 + el;
    const u32* P32 = (const u32*)Pall;
    const u32* rowT = P32 + (size_t)esrc[el] * 9 * 256 + tag * 128;
    const u32* rowB = P32 + (size_t)edst[el] * 9 * 256 + tag * 128 + 64;
    #pragma unroll
    for (int q = 0; q < 8; ++q) {
      int p = pp * 8 + q;
      float m0a = 0.f, m0b = 0.f;
      if (e < NE) {
        #pragma unroll
        for (int j = 0; j < 9; ++j) {
          float w = wig0s[el][j];
          u32 ut = rowT[j * 256 + p];
          u32 ub = rowB[j * 256 + p];
          m0a += w * (bf_lo(ut) + bf_lo(ub));
          m0b += w * (bf_hi(ut) + bf_hi(ub));
        }
        u32 ur = radP[((size_t)tag * NE * CC) / 2 + (size_t)e * 64 + p];
        m0a *= bf_lo(ur);
        m0b *= bf_hi(ur);
      }
      Asf[el * AP + 2 * p]     = m0a;
      Asf[el * AP + 2 * p + 1] = m0b;
    }
  }
  __syncthreads();
  int rq = t & 7, cq = t >> 3;
  int r0 = rq * 4, c0 = cq * 4;
  for (int cp = 0; cp < 2; ++cp) {
    for (int i = t; i < 128 * 64; i += 256) {
      int k = i >> 6, c2 = i & 63;
      Bs[k * BP + c2] = pack2(B[k * 256 + cp * 128 + 2 * c2], B[k * 256 + cp * 128 + 2 * c2 + 1]);
    }
    __syncthreads();
    float a4[16] = {};
    gemm_32x128(Asf, Bs, r0, cq, a4);
    int ca = cp * 128 + c0;
    int h = ca >> 5;
    #pragma unroll
    for (int i = 0; i < 4; ++i) {
      float psum = 0.f;
      #pragma unroll
      for (int j = 0; j < 4; ++j) {
        float aa = a4[i * 4 + j];
        aa = (aa >= 0.f) ? aa : 0.2f * aa;      // leaky_relu 0.2
        psum += aa * av[h * 32 + ((ca + j) & 31)];
      }
      atomicAdd(&ltile[r0 + i][h], psum);
    }
    __syncthreads();
  }
  {
    int el = t >> 3, hh = t & 7;
    int e = e0 + el;
    if (e < NE) {
      float lg = ltile[el][hh];
      logits[(size_t)tag * NE * NH + (size_t)e * NH + hh] = lg;
      atomicMax(&mkey[tag * NN * NH + edst[el] * NH + hh], encf(lg));
    }
  }
}

// ---------- K5: ex = exp(logit - m[dst]); den = segment_sum ----------
__global__ void k5_ex(const float* __restrict__ logits, const u32* __restrict__ mkey,
                      const int* __restrict__ eidx, float* __restrict__ ex, float* __restrict__ den)
{
  int idx = blockIdx.x * 256 + threadIdx.x;
  if (idx >= 2 * NE * NH) return;
  int h = idx & 7;
  int e = (idx >> 3) % NE;
  int tag = idx / (NE * NH);
  int d = eidx[NE + e];
  float m = decf(mkey[tag * NN * NH + d * NH + h]);
  float v = __expf(logits[idx] - m);
  ex[idx] = v;
  atomicAdd(&den[tag * NN * NH + d * NH + h], v);
}

// ---------- K6: per-edge main ----------
__global__ __launch_bounds__(256) void k6_main(const u16* __restrict__ Pall,
                                               const float* __restrict__ wig,
                                               const u32* __restrict__ radP,
                                               const float* __restrict__ wpv,
                                               const float* __restrict__ ex,
                                               const float* __restrict__ den,
                                               const int* __restrict__ eidx,
                                               float* __restrict__ acc)
{
  __shared__ float wigs[4][81];
  int t = threadIdx.x;
  int tag = blockIdx.y;
  int eb = blockIdx.x * 4;
  for (int i = t; i < 4 * 81; i += 256) {
    int el = i / 81, q = i % 81;
    wigs[el][q] = wig[(size_t)(eb + el) * 81 + q];
  }
  __syncthreads();
  int wid = t >> 6, lane = t & 63;
  int e = eb + wid;
  int s = eidx[e], d = eidx[NE + e];
  const u32* P32 = (const u32*)Pall;
  const u32* rowT = P32 + (size_t)s * 9 * 256 + tag * 128;
  const u32* rowB = P32 + (size_t)d * 9 * 256 + tag * 128 + 64;
  float S0[9], S1[9];
  #pragma unroll
  for (int j = 0; j < 9; ++j) {
    u32 ut = rowT[j * 256 + lane];
    u32 ub = rowB[j * 256 + lane];
    S0[j] = bf_lo(ut) + bf_lo(ub);
    S1[j] = bf_hi(ut) + bf_hi(ub);
  }
  float m0[9], m1[9];
  #pragma unroll
  for (int i = 0; i < 9; ++i) {
    float a0 = 0.f, a1 = 0.f;
    #pragma unroll
    for (int j = 0; j < 9; ++j) {
      float w = wigs[wid][i * 9 + j];
      a0 += w * S0[j];
      a1 += w * S1[j];
    }
    m0[i] = a0; m1[i] = a1;
  }
  u32 ur = radP[((size_t)tag * NE * CC) / 2 + (size_t)e * 64 + lane];
  float r0v = bf_lo(ur), r1v = bf_hi(ur);
  #pragma unroll
  for (int i = 0; i < 9; ++i) { m0[i] *= r0v; m1[i] *= r1v; }
  float g0 = sigmoidf_(m0[0]);
  float g1 = sigmoidf_(m1[0]);
  float gA = 0.f, gB = 0.f;
  #pragma unroll
  for (int h = 0; h < NH; ++h) {
    float at = ex[(size_t)tag * NE * NH + (size_t)e * NH + h]
             / (den[tag * NN * NH + d * NH + h] + 1e-9f);
    gA += wpv[tag * 1024 + (2 * lane) * 8 + h] * at;
    gB += wpv[tag * 1024 + (2 * lane + 1) * 8 + h] * at;
  }
  float sp[9];
  #pragma unroll
  for (int i = 0; i < 9; ++i)
    sp[i] = m0[i] * g0 * gA + m1[i] * g1 * gB;   // val = msg * sigmoid(msg0) (row0 = silu)
  #pragma unroll
  for (int off = 1; off < 64; off <<= 1) {
    #pragma unroll
    for (int i = 0; i < 9; ++i)
      sp[i] += __shfl_xor(sp[i], off, 64);
  }
  if (lane < 3) {
    int ip = lane + 1;
    float y = 0.f;
    #pragma unroll
    for (int j = 0; j < 9; ++j)
      y += wigs[wid][j * 9 + ip] * sp[j];
    atomicAdd(&acc[tag * NN * 3 + d * 3 + lane], y);
  }
}

// ---------- K7: masked select, f32 out ----------
__global__ void k7_out(const float* __restrict__ acc, const void* __restrict__ mask,
                       const int* __restrict__ flag, float* __restrict__ out)
{
  int idx = blockIdx.x * 256 + threadIdx.x;
  if (idx >= NN * 3) return;
  int n = idx / 3;
  bool msk;
  if (*flag) msk = ((const unsigned char*)mask)[n] != 0;
  else       msk = ((const int*)mask)[n] != 0;
  out[idx] = msk ? acc[NN * 3 + idx] : acc[idx];
}

extern "C" void kernel_launch(void* const* d_in, const int* in_sizes, int n_in,
                              void* d_out, int out_size, void* d_ws, size_t ws_size,
                              hipStream_t stream)
{
  (void)hipGetLastError();   // clear sticky error state

  // ---- input-order detection: setup_inputs() dict order vs reference signature order ----
  bool setup_order = (n_in >= 22) && (in_sizes[3] == NN) && (in_sizes[4] == 2 * NE);
  const float *x, *edist, *wig;
  const int *zn, *eidx;
  const void *mask;
  const float *ae_v, *wr1_v, *wr2_v, *wmsg_v, *wal_v, *av_v, *wval_v, *wproj_v;
  const float *ae_d, *wr1_d, *wr2_d, *wmsg_d, *wal_d, *av_d, *wval_d, *wproj_d;
  x     = (const float*)d_in[0];
  edist = (const float*)d_in[1];
  wig   = (const float*)d_in[2];
  if (setup_order) {
    zn      = (const int*)d_in[3];
    eidx    = (const int*)d_in[4];
    mask    = d_in[5];
    ae_v    = (const float*)d_in[6];   wr1_v  = (const float*)d_in[7];
    wr2_v   = (const float*)d_in[8];   wmsg_v = (const float*)d_in[9];
    wal_v   = (const float*)d_in[10];  av_v   = (const float*)d_in[11];
    wval_v  = (const float*)d_in[12];  wproj_v= (const float*)d_in[13];
    ae_d    = (const float*)d_in[14];  wr1_d  = (const float*)d_in[15];
    wr2_d   = (const float*)d_in[16];  wmsg_d = (const float*)d_in[17];
    wal_d   = (const float*)d_in[18];  av_d   = (const float*)d_in[19];
    wval_d  = (const float*)d_in[20];  wproj_d= (const float*)d_in[21];
  } else {                      // reference() signature order
    ae_v    = (const float*)d_in[3];   wr1_v  = (const float*)d_in[4];
    wr2_v   = (const float*)d_in[5];   wmsg_v = (const float*)d_in[6];
    wal_v   = (const float*)d_in[7];   av_v   = (const float*)d_in[8];
    wval_v  = (const float*)d_in[9];   wproj_v= (const float*)d_in[10];
    ae_d    = (const float*)d_in[11];  wr1_d  = (const float*)d_in[12];
    wr2_d   = (const float*)d_in[13];  wmsg_d = (const float*)d_in[14];
    wal_d   = (const float*)d_in[15];  av_d   = (const float*)d_in[16];
    wval_d  = (const float*)d_in[17];  wproj_d= (const float*)d_in[18];
    zn      = (const int*)d_in[19];
    eidx    = (const int*)d_in[20];
    mask    = d_in[21];
  }

  // ---- workspace layout (bytes) ----
  const size_t OFF_P    = 0;              // 46,080,000  (45000*512 bf16)
  const size_t OFF_H1   = 46080000;       // 25,600,000  (2*NE*128 bf16, rad in-place)
  const size_t OFF_LOG  = 71680000;       //  3,200,000
  const size_t OFF_EX   = 74880000;       //  3,200,000
  const size_t OFF_MK   = 78080000;       //    320,000
  const size_t OFF_DEN  = 78400000;       //    320,000
  const size_t OFF_ACC  = 78720000;       //    120,000
  const size_t OFF_RADZ = 78840000;       //    204,800
  const size_t OFF_WPV  = 79044800;       //      8,192
  const size_t OFF_FLAG = 79052992;       //         64
  const size_t NEEDED   = 79053056;

  const size_t out_bytes = (size_t)out_size * sizeof(float);

  if (d_ws == nullptr || ws_size < NEEDED) {
    // signal "workspace too small": f32 pattern 0x66666666 ~ 2.72e23
    hipMemsetAsync(d_out, 0x66, out_bytes, stream);
    return;
  }

  char* ws = (char*)d_ws;
  u16*   Pall   = (u16*)(ws + OFF_P);
  u32*   h1rad  = (u32*)(ws + OFF_H1);
  float* logits = (float*)(ws + OFF_LOG);
  float* ex     = (float*)(ws + OFF_EX);
  u32*   mkey   = (u32*)(ws + OFF_MK);
  float* den    = (float*)(ws + OFF_DEN);
  float* acc    = (float*)(ws + OFF_ACC);
  float* radz   = (float*)(ws + OFF_RADZ);
  float* wpv    = (float*)(ws + OFF_WPV);
  int*   flag   = (int*)(ws + OFF_FLAG);

  k0_tables<<<951, 256, 0, stream>>>(ae_v, wr1_v, ae_d, wr1_d,
                                     wval_v, wproj_v, wval_d, wproj_d,
                                     radz, wpv, mkey, den, acc);
  k0_flag<<<1, 256, 0, stream>>>((const u32*)mask, flag);
  k1_nodepre<<<dim3(1407, 4), 256, 0, stream>>>(x, wmsg_v, wmsg_d, Pall);
  k2_rad1<<<dim3(1563, 2), 256, 0, stream>>>(edist, wr1_v, wr1_d, eidx, zn, radz, h1rad);
  k3_rad2<<<dim3(1563, 2), 256, 0, stream>>>(h1rad, wr2_v, wr2_d);
  k4_logits<<<dim3(1563, 2), 256, 0, stream>>>(Pall, wig, h1rad, wal_v, wal_d, av_v, av_d,
                                               eidx, logits, mkey);
  k5_ex<<<3125, 256, 0, stream>>>(logits, mkey, eidx, ex, den);
  k6_main<<<dim3(12500, 2), 256, 0, stream>>>(Pall, wig, h1rad, wpv, ex, den, eidx, acc);
  k7_out<<<59, 256, 0, stream>>>(acc, mask, flag, (float*)d_out);

  // ---- diagnostic: if ANY launch failed, overwrite output with loud pattern ----
  if (hipGetLastError() != hipSuccess) {
    hipMemsetAsync(d_out, 0x77, out_bytes, stream);   // f32 ~ 5.0e33
  }
}